// Round 1
// 932.456 us; speedup vs baseline: 1.1053x; 1.1053x over previous
//
#include <hip/hip_runtime.h>
#include <cmath>

#define NROWS 100000
#define DIM   1024
#define LH    128
#define NSEG  16
#define EPSF  1e-16f

#define OUT_OFF   0
#define SCORE_OFF (NSEG * DIM)            /* 16384   */
#define SM_OFF    (SCORE_OFF + NROWS)     /* 116384  */
#define FEAT_OFF  (SM_OFF + NROWS)        /* 216384  */

typedef __attribute__((ext_vector_type(4))) float floatx4;
typedef __attribute__((ext_vector_type(8))) short shortx8;

__device__ __forceinline__ unsigned short f2bf(float x) {
    unsigned u = __float_as_uint(x);
    u += 0x7FFFu + ((u >> 16) & 1u);          // round-to-nearest-even
    return (unsigned short)(u >> 16);
}
__device__ __forceinline__ unsigned enc_f32(float f) {   // monotone float->uint
    unsigned u = __float_as_uint(f);
    return (u & 0x80000000u) ? ~u : (u | 0x80000000u);
}
__device__ __forceinline__ float dec_f32(unsigned e) {
    unsigned u = (e & 0x80000000u) ? (e ^ 0x80000000u) : ~e;
    return __uint_as_float(u);
}
// async global->LDS, 16B per lane, linear dest (wave-uniform base + lane*16)
__device__ __forceinline__ void gload_lds16(const void* g, void* l) {
    __builtin_amdgcn_global_load_lds(
        (const __attribute__((address_space(1))) void*)g,
        (__attribute__((address_space(3))) void*)l, 16, 0, 0);
}

// ---------------------------------------------------------------- init -----
// Repack Wa,Wb (fp32) -> bf16 in MFMA-fragment order so score_kernel can
// stage each 64-wide K-chunk as a LINEAR 32KB global_load_lds copy.
// Element W[r][k] (r<128: Wa, else Wb) lands at
//   chunk*16384 + t*1024 + ks*512 + lane*8 + e
// with chunk=k>>6, ks=(k>>5)&1, q=(k>>3)&3, e=k&7, t=r>>4, c=r&15,
// lane=q*16+c — exactly the 16x16x32 bf16 B-fragment slot (lane reads its own
// 16B => conflict-free ds_read_b128). Grid: 128 blocks x 256 (32768 threads,
// one thread per 8 consecutive k of one row).
__global__ void init_kernel(const float* __restrict__ Wa,
                            const float* __restrict__ Wb,
                            unsigned short* __restrict__ wbf,
                            unsigned* __restrict__ segmax,
                            float* __restrict__ denom,
                            float* __restrict__ out) {
    const int idx = blockIdx.x * 256 + threadIdx.x;      // 0..32767
    {
        const int r  = idx >> 7;        // 0..255
        const int kg = idx & 127;       // k-group of 8
        const int k  = kg << 3;
        const float* src = (r < LH) ? (Wa + (size_t)r * DIM + k)
                                    : (Wb + (size_t)(r - LH) * DIM + k);
        const floatx4 v0 = *(const floatx4*)src;
        const floatx4 v1 = *(const floatx4*)(src + 4);
        const int chunk = kg >> 3;
        const int ks    = (kg >> 2) & 1;
        const int q     = kg & 3;
        const int t     = r >> 4;
        const int c     = r & 15;
        shortx8 o;
        o[0] = (short)f2bf(v0[0]); o[1] = (short)f2bf(v0[1]);
        o[2] = (short)f2bf(v0[2]); o[3] = (short)f2bf(v0[3]);
        o[4] = (short)f2bf(v1[0]); o[5] = (short)f2bf(v1[1]);
        o[6] = (short)f2bf(v1[2]); o[7] = (short)f2bf(v1[3]);
        *(shortx8*)(wbf + (size_t)chunk * 16384 + t * 1024 + ks * 512
                        + (q * 16 + c) * 8) = o;
    }
    if (idx < NSEG * DIM) out[OUT_OFF + idx] = 0.f;
    if (idx < NSEG) { segmax[idx] = 0u; denom[idx] = 0.f; }
}

// --------------------------------------------------------------- score -----
// Block = 256 thr (4 waves), 64 rows/block, wave w owns rows 16w..16w+15.
// A never touches LDS: each lane loads its own fp32 A-fragment straight from
// global (4 lanes of a q-group cover a contiguous 128B row segment), echoes
// it to d_out, converts to bf16 in-register. W chunk (32KB, fragment-ordered
// by init) staged via linear global_load_lds: no VGPR round trip, no bank
// conflicts. LDS ~34KB -> 4 blocks/CU.
__launch_bounds__(256)
__global__ void score_kernel(const float* __restrict__ feature,
                             const int* __restrict__ batch,
                             const unsigned short* __restrict__ wbf,
                             const float* __restrict__ ba,
                             const float* __restrict__ bb,
                             const float* __restrict__ wc,
                             const float* __restrict__ bc,
                             float* __restrict__ outp,
                             unsigned* __restrict__ segmax) {
    __shared__ __align__(16) unsigned short sW[16384];   // 32 KB
    __shared__ float sBias[3 * LH];
    __shared__ float sScore[64];
    __shared__ int   sBatch[64];
    __shared__ unsigned sMax[NSEG];

    const int tid   = threadIdx.x;
    const int wave  = tid >> 6;
    const int lane  = tid & 63;
    const int q     = lane >> 4;    // k-group within fragment
    const int c     = lane & 15;    // A-row within wave tile / B-col
    const int row0  = blockIdx.x * 64;
    const int myrow = row0 + wave * 16 + c;
    const bool inb  = myrow < NROWS;

    if (tid < LH) {
        sBias[tid]          = ba[tid];
        sBias[LH + tid]     = bb[tid];
        sBias[2 * LH + tid] = wc[tid];
    }
    if (tid < NSEG) sMax[tid] = 0u;

    floatx4 acc[16];
#pragma unroll
    for (int t = 0; t < 16; ++t)
#pragma unroll
        for (int i = 0; i < 4; ++i) acc[t][i] = 0.f;

    const float* arow = feature + (size_t)myrow * DIM;
    float*       erow = outp + FEAT_OFF + (size_t)myrow * DIM;

    for (int k0 = 0; k0 < DIM; k0 += 64) {
        __syncthreads();                       // prev chunk's LDS reads done
        // ---- stage W chunk: linear 32KB async copy ----
        const unsigned short* gsrc = wbf + (size_t)(k0 >> 6) * 16384;
#pragma unroll
        for (int p = 0; p < 8; ++p) {
            const int off = (p * 256 + tid) * 8;      // element offset
            gload_lds16(gsrc + off, &sW[off]);
        }
        // ---- A: direct fp32 fragment load + echo + in-reg bf16 convert ----
        shortx8 afrag[2];
#pragma unroll
        for (int ks = 0; ks < 2; ++ks) {
            const int kk = k0 + ks * 32 + q * 8;
            floatx4 v0 = {0.f, 0.f, 0.f, 0.f};
            floatx4 v1 = {0.f, 0.f, 0.f, 0.f};
            if (inb) {
                v0 = *(const floatx4*)(arow + kk);
                v1 = *(const floatx4*)(arow + kk + 4);
                *(floatx4*)(erow + kk)     = v0;
                *(floatx4*)(erow + kk + 4) = v1;
            }
            afrag[ks][0] = (short)f2bf(v0[0]);
            afrag[ks][1] = (short)f2bf(v0[1]);
            afrag[ks][2] = (short)f2bf(v0[2]);
            afrag[ks][3] = (short)f2bf(v0[3]);
            afrag[ks][4] = (short)f2bf(v1[0]);
            afrag[ks][5] = (short)f2bf(v1[1]);
            afrag[ks][6] = (short)f2bf(v1[2]);
            afrag[ks][7] = (short)f2bf(v1[3]);
        }
        __syncthreads();                       // W staged (vmcnt drained here)
        // ---- MFMA: 2 k-steps x 16 col-tiles, conflict-free ds_read_b128 ----
#pragma unroll
        for (int ks = 0; ks < 2; ++ks) {
#pragma unroll
            for (int t = 0; t < 16; ++t) {
                shortx8 b = *(const shortx8*)&sW[t * 1024 + ks * 512 + lane * 8];
                acc[t] = __builtin_amdgcn_mfma_f32_16x16x32_bf16(afrag[ks], b,
                                                                 acc[t], 0, 0, 0);
            }
        }
    }

    // ---- epilogue: bias + sigmoid*tanh gate + Wc dot (verified path) ----
    float p4[4] = {0.f, 0.f, 0.f, 0.f};
#pragma unroll
    for (int t = 0; t < 8; ++t) {
        const int col = t * 16 + c;
        const float bav = sBias[col];
        const float bbv = sBias[LH + col];
        const float wcv = sBias[2 * LH + col];
#pragma unroll
        for (int i = 0; i < 4; ++i) {
            float u = acc[t][i] + bav;         // a-logit
            float v = acc[t + 8][i] + bbv;     // b-logit
            float sg = 1.f / (1.f + __expf(-u));
            float th = tanhf(v);
            p4[i] += sg * th * wcv;
        }
    }
#pragma unroll
    for (int i = 0; i < 4; ++i) {              // reduce over 16 cols
        p4[i] += __shfl_xor(p4[i], 1, 16);
        p4[i] += __shfl_xor(p4[i], 2, 16);
        p4[i] += __shfl_xor(p4[i], 4, 16);
        p4[i] += __shfl_xor(p4[i], 8, 16);
    }

    __syncthreads();
    if (tid < 64) sBatch[tid] = -1;
    __syncthreads();

    const float bcv = bc[0];
    if (c == 0) {
#pragma unroll
        for (int i = 0; i < 4; ++i) {
            const int r    = wave * 16 + q * 4 + i;
            const int grow = row0 + r;
            if (grow < NROWS) {
                const float s = p4[i] + bcv;
                outp[SCORE_OFF + grow] = s;
                sScore[r] = s;
                sBatch[r] = batch[grow];
            }
        }
    }
    __syncthreads();
    if (tid < 64 && sBatch[tid] >= 0)
        atomicMax(&sMax[sBatch[tid]], enc_f32(sScore[tid]));
    __syncthreads();
    if (tid < NSEG && sMax[tid] != 0u)
        atomicMax(&segmax[tid], sMax[tid]);
}

// ----------------------------------------------------------------- exp -----
__global__ void exp_kernel(const float* __restrict__ score,
                           const int* __restrict__ batch,
                           const unsigned* __restrict__ segmax,
                           float* __restrict__ evals,
                           float* __restrict__ denom) {
    __shared__ float sden[NSEG];
    const int tid = threadIdx.x;
    const int idx = blockIdx.x * 256 + tid;
    if (tid < NSEG) sden[tid] = 0.f;
    __syncthreads();
    if (idx < NROWS) {
        const int b = batch[idx];
        const float m = dec_f32(segmax[b]);
        const float e = expf(score[idx] - m);
        evals[idx] = e;
        atomicAdd(&sden[b], e);
    }
    __syncthreads();
    if (tid < NSEG && sden[tid] != 0.f) atomicAdd(&denom[tid], sden[tid]);
}

// ---------------------------------------------------------------- wsum -----
// 128 rows/block, thread owns 4 cols. batch is SORTED, so 99.7% of blocks
// span exactly one segment: branch-free unroll-8 fast path with one atomic
// flush. Multi-segment / tail blocks take the (verified) flush-on-change
// slow path. Path choice is block-uniform -> no divergence.
__launch_bounds__(256)
__global__ void wsum_kernel(const float* __restrict__ feature,
                            const int* __restrict__ batch,
                            const float* __restrict__ denom,
                            float* __restrict__ evals,   // in: e, out: softmax
                            float* __restrict__ outp) {
    __shared__ float sw[128];
    __shared__ int   sb[128];
    const int tid = threadIdx.x;
    const int r0  = blockIdx.x * 128;

    if (tid < 128) {
        const int row = r0 + tid;
        if (row < NROWS) {
            const int b = batch[row];
            const float w = evals[row] / (denom[b] + EPSF);
            evals[row] = w;                    // score_softmax output
            sw[tid] = w;
            sb[tid] = b;
        } else {
            sw[tid] = 0.f;
            sb[tid] = -1;
        }
    }
    __syncthreads();

    const int cc = tid * 4;
    const int b0 = sb[0];                      // always valid (r0 < NROWS)
    const int bL = sb[127];
    floatx4 acc; acc[0] = acc[1] = acc[2] = acc[3] = 0.f;

    if (b0 == bL) {
        // ---- fast path: whole block in one segment, fully in-range ----
        const float* fp = feature + (size_t)r0 * DIM + cc;
#pragma unroll 8
        for (int r = 0; r < 128; ++r) {
            const floatx4 f = *(const floatx4*)(fp + (size_t)r * DIM);
            const float w = sw[r];
            acc[0] += w * f[0];
            acc[1] += w * f[1];
            acc[2] += w * f[2];
            acc[3] += w * f[3];
        }
#pragma unroll
        for (int j = 0; j < 4; ++j)
            atomicAdd(&outp[OUT_OFF + b0 * DIM + cc + j], acc[j]);
    } else {
        // ---- slow path: segment change (or tail) inside block ----
        int curseg = -1;
        for (int r = 0; r < 128; ++r) {
            const int b = sb[r];
            if (b < 0) break;                  // sorted: tail only
            if (b != curseg) {
                if (curseg >= 0) {
#pragma unroll
                    for (int j = 0; j < 4; ++j)
                        atomicAdd(&outp[OUT_OFF + curseg * DIM + cc + j], acc[j]);
                }
                curseg = b;
                acc[0] = acc[1] = acc[2] = acc[3] = 0.f;
            }
            const floatx4 f = *(const floatx4*)(feature + (size_t)(r0 + r) * DIM + cc);
            const float w = sw[r];
            acc[0] += w * f[0];
            acc[1] += w * f[1];
            acc[2] += w * f[2];
            acc[3] += w * f[3];
        }
        if (curseg >= 0) {
#pragma unroll
            for (int j = 0; j < 4; ++j)
                atomicAdd(&outp[OUT_OFF + curseg * DIM + cc + j], acc[j]);
        }
    }
}

// -------------------------------------------------------------- launch -----
extern "C" void kernel_launch(void* const* d_in, const int* in_sizes, int n_in,
                              void* d_out, int out_size, void* d_ws, size_t ws_size,
                              hipStream_t stream) {
    const float* feature = (const float*)d_in[0];
    const int*   batch   = (const int*)d_in[1];
    const float* Wa      = (const float*)d_in[2];
    const float* ba      = (const float*)d_in[3];
    const float* Wb      = (const float*)d_in[4];
    const float* bb      = (const float*)d_in[5];
    const float* Wc      = (const float*)d_in[6];
    const float* bc      = (const float*)d_in[7];
    float* out = (float*)d_out;

    unsigned short* wbf = (unsigned short*)d_ws;                       // 512 KB
    unsigned* segmax = (unsigned*)((char*)d_ws + 2 * LH * DIM * 2);    // 16 u32
    float*    denom  = (float*)((char*)d_ws + 2 * LH * DIM * 2 + 64);  // 16 f32

    init_kernel<<<128, 256, 0, stream>>>(Wa, Wb, wbf, segmax, denom, out);
    score_kernel<<<(NROWS + 63) / 64, 256, 0, stream>>>(feature, batch, wbf, ba, bb, Wc, bc, out, segmax);
    exp_kernel<<<(NROWS + 255) / 256, 256, 0, stream>>>(out + SCORE_OFF, batch, segmax, out + SM_OFF, denom);
    wsum_kernel<<<(NROWS + 127) / 128, 256, 0, stream>>>(feature, batch, denom, out + SM_OFF, out);
}